// Round 1
// baseline (211.390 us; speedup 1.0000x reference)
//
#include <hip/hip_runtime.h>
#include <hip/hip_fp16.h>
#include <math.h>

#define HH 512
#define WW 512
#define BB 4
#define NPIX (BB * HH * WW)

#define HS 8                 // core rows per wave (must keep R0 % 4 == 0)
#define NSX 9                // strips: 9 x 60 core cols >= 512
#define NBAND (HH / HS)      // 64
#define NWAVES (NSX * NBAND * BB)   // 2304
#define NBLK (NWAVES / 4)           // 576

constexpr float TAUf   = 0.01f;
constexpr float RHOf   = 1.99f;
constexpr float SIGMAf = (float)(1.0 / 0.01 / 72.0);
constexpr float INV1PT = (float)(1.0 / 1.01);

__device__ __forceinline__ float cf(__half h) { return __half2float(h); }
__device__ __forceinline__ float SD(float v) { return __shfl_down(v, 1, 64); }  // lane+1
__device__ __forceinline__ float SUp(float v) { return __shfl_up(v, 1, 64); }   // lane-1

// MODE: 0 = iter 0 (analytic x=y,r=0,u=0); 1 = mid iter; 2 = last iter (x-only, f32 out)
template <int MODE>
__global__ __launch_bounds__(256) void sweep(
    const float* __restrict__ y, const int* __restrict__ ths_p,
    const __half* __restrict__ x2_in, const __half* __restrict__ r2_in,
    const __half* __restrict__ u_in,
    __half* __restrict__ x2_out, __half* __restrict__ r2_out,
    __half* __restrict__ u_out, float* __restrict__ xout)
{
    const int tid  = threadIdx.x;
    const int lane = tid & 63;
    const int wid  = blockIdx.x * 4 + (tid >> 6);
    const int sx   = wid % NSX;
    const int t2   = wid / NSX;
    const int band = t2 & (NBAND - 1);
    const int b    = t2 / NBAND;
    const int R0   = band * HS;               // multiple of 4 -> ring slots are compile-time
    const int w    = sx * 60 - 2 + lane;
    const int boff = b * (HH * WW);
    const bool wok = ((unsigned)w) < (unsigned)WW;
    const float mA = (w >= 1 && w < WW) ? 1.f : 0.f;       // (w>=1) guard
    const float mB = (w >= 0 && w < WW - 1) ? 1.f : 0.f;   // (w<W-1) guard
    const bool cok = (lane >= 2) && (lane < 62) && (w < WW);

    const float ths     = (float)ths_p[0];
    const float inv_tl1 = 1.0f / (TAUf * (ths * 0.1f));
    const float inv_l2  = 1.0f / (ths * 0.15f);

    // register rings
    float uf0[4], uf1[4], uf2[4], uf3[4];     // u rows (unpacked f32)
    float i0r[2], i1r[2];                     // eps2_adj rows
    float sr[4], t0r[4], t1r[4];              // s, t rows
    #pragma unroll
    for (int q = 0; q < 4; ++q) { uf0[q]=uf1[q]=uf2[q]=uf3[q]=0.f; sr[q]=t0r[q]=t1r[q]=0.f; }
    i0r[0]=i0r[1]=i1r[0]=i1r[1]=0.f;

    auto uload = [&](int row) -> uint2 {
        uint2 z; z.x = 0u; z.y = 0u;
        if (((unsigned)row) < (unsigned)HH && wok)
            z = *(const uint2*)(u_in + 4 * (size_t)(boff + row * WW + w));
        return z;
    };
    auto unpk = [&](int slot, uint2 raw) {
        __half2 lo = *(reinterpret_cast<__half2*>(&raw.x));
        __half2 hi = *(reinterpret_cast<__half2*>(&raw.y));
        uf0[slot] = __low2float(lo); uf1[slot] = __high2float(lo);
        uf2[slot] = __low2float(hi); uf3[slot] = __high2float(hi);
    };
    // i(rr): islot, c = rr&3 (u row rr), d = (rr+1)&3, uu_ = (rr-1)&3
    auto compI = [&](int rr, int islot, int c, int d, int uu_) {
        if (((unsigned)rr) < (unsigned)HH) {
            float hD  = (rr < HH - 1) ? 1.f : 0.f;
            float u1c = uf1[c], u2c = uf2[c];
            i0r[islot] = uf0[c] - uf0[d] - SD(u1c) + mA * u1c;
            i1r[islot] = u2c - SD(u2c) - hD * uf3[c] + uf3[uu_];
        } else { i0r[islot] = 0.f; i1r[islot] = 0.f; }
    };

    if (MODE == 2) {
        // ---- last iter: only x output (f32) ----
        unpk(2, uload(R0 - 2));
        unpk(3, uload(R0 - 1));
        unpk(0, uload(R0));
        compI(R0 - 1, 1, 3, 0, 2);
        uint2 pu = uload(R0 + 1);
        float pyv, px2;
        {
            int row = R0; bool ok = wok;   // R0 in range always
            int idx = boff + row * WW + w;
            pyv = ok ? y[idx] : 0.f;
            px2 = ok ? cf(x2_in[idx]) : 0.f;
        }
        #pragma unroll
        for (int k = 0; k < HS; ++k) {
            const int rr = R0 + k;
            unpk((k + 1) & 3, pu);
            uint2 nu = uload(rr + 2);
            float yv = pyv, x2v = px2;
            if (k < HS - 1) {
                int row = rr + 1; bool ok = wok;
                int idx = boff + row * WW + w;
                pyv = ok ? y[idx] : 0.f;
                px2 = ok ? cf(x2_in[idx]) : 0.f;
            }
            compI(rr, k & 1, k & 3, (k + 1) & 3, (k + 3) & 3);
            float hD = (rr < HH - 1) ? 1.f : 0.f;
            float i0c = i0r[k & 1], i1c = i1r[k & 1], i1u = i1r[(k + 1) & 1];
            float i0l = SUp(i0c);
            float na = TAUf * (mA * i0l - mB * i0c + i1u - hD * i1c);
            float x = (x2v - na + TAUf * yv) * INV1PT;
            if (cok) xout[boff + rr * WW + w] = x2v + RHOf * (x - x2v);
            pu = nu;
        }
        return;
    }

    // s,t(rr); relax writes on core rows
    auto compS = [&](int rr, int ss_, int isc, int isp,
                     float yv, float x2v, float r20v, float r21v, bool coreRow) {
        if (((unsigned)rr) < (unsigned)HH) {
            if (MODE == 0) {
                sr[ss_] = yv; t0r[ss_] = 0.f; t1r[ss_] = 0.f;
                if (coreRow && cok) {
                    int idx = boff + rr * WW + w;
                    x2_out[idx] = __float2half(yv);
                    *(__half2*)(r2_out + 2 * (size_t)idx) = __floats2half2_rn(0.f, 0.f);
                }
            } else {
                float hD = (rr < HH - 1) ? 1.f : 0.f;
                float i0c = i0r[isc], i1c = i1r[isc], i1u = i1r[isp];
                float i0l = SUp(i0c);
                float na = TAUf * (mA * i0l - mB * i0c + i1u - hD * i1c);
                float x = (x2v - na + TAUf * yv) * INV1PT;
                float rr0 = r20v + TAUf * i0c;
                float rr1 = r21v + TAUf * i1c;
                float mag = sqrtf(rr0 * rr0 + rr1 * rr1) * inv_tl1;
                float rinv = 1.0f / fmaxf(mag, 1.0f);
                float r0 = rr0 - rr0 * rinv;
                float r1 = rr1 - rr1 * rinv;
                sr[ss_]  = 2.f * x  - x2v;
                t0r[ss_] = 2.f * r0 - r20v;
                t1r[ss_] = 2.f * r1 - r21v;
                if (coreRow && cok) {
                    int idx = boff + rr * WW + w;
                    x2_out[idx] = __float2half(x2v + RHOf * (x - x2v));
                    *(__half2*)(r2_out + 2 * (size_t)idx) = __floats2half2_rn(
                        r20v + RHOf * (r0 - r20v), r21v + RHOf * (r1 - r21v));
                }
            }
        } else { sr[ss_] = 0.f; t0r[ss_] = 0.f; t1r[ss_] = 0.f; }
    };

    // u'(ro): sc_=ro&3, sd_=(ro+1)&3, suu=(ro-1)&3, sdd_=(ro+2)&3, uslot=ro&3
    auto compU = [&](int ro, int sc_, int sd_, int suu, int sdd_, int uslot) {
        float hD  = (ro < HH - 1) ? 1.f : 0.f;
        float hD1 = (ro + 1 < HH - 1) ? 1.f : 0.f;
        float sc = sr[sc_], sd = sr[sd_], su = sr[suu], s2 = sr[sdd_];
        float t0c = t0r[sc_], t0u = t0r[suu];
        float t1c = t1r[sc_], t1d = t1r[sd_];
        float sc_p = SD(sc), su_p = SD(su);
        float sc_m = SUp(sc), sd_m = SUp(sd);
        float t0c_m = SUp(t0c), t1c_m = SUp(t1c);
        float v0c = mB * (sc_p - sc) - t0c;
        float v1c = hD * (sd - sc) - t1c;
        float v0u = mB * (su_p - su) - t0u;
        float v0l = (sc - sc_m) - t0c_m;
        float v1l = hD * (sd_m - sc_m) - t1c_m;
        float v1d = hD1 * (s2 - sd) - t1d;
        float G0 = v0c - v0u;
        float G1 = mA * (v0c - v0l);
        float G2 = v1c - mA * v1l;
        float G3 = hD * (v1d - v1c);
        float u0v, u1v, u2v, u3v;
        if (MODE == 0) { u0v = u1v = u2v = u3v = 0.f; }
        else { u0v = uf0[uslot]; u1v = uf1[uslot]; u2v = uf2[uslot]; u3v = uf3[uslot]; }
        float uu0 = u0v + SIGMAf * G0;
        float uu1 = u1v + SIGMAf * G1;
        float uu2 = u2v + SIGMAf * G2;
        float uu3 = u3v + SIGMAf * G3;
        float mag = sqrtf(uu0 * uu0 + uu1 * uu1 + uu2 * uu2 + uu3 * uu3) * inv_l2;
        float ui = 1.0f / fmaxf(mag, 1.0f);
        if (cok) {
            int idx = boff + ro * WW + w;
            __half2 lo = __floats2half2_rn(u0v + RHOf * (uu0 * ui - u0v),
                                           u1v + RHOf * (uu1 * ui - u1v));
            __half2 hi = __floats2half2_rn(u2v + RHOf * (uu2 * ui - u2v),
                                           u3v + RHOf * (uu3 * ui - u3v));
            uint2 st; st.x = *(unsigned*)&lo; st.y = *(unsigned*)&hi;
            *(uint2*)(u_out + 4 * (size_t)idx) = st;
        }
    };

    // ---- prologue ----
    uint2 pu; pu.x = 0u; pu.y = 0u;
    float pyv = 0.f, px2 = 0.f, pr0 = 0.f, pr1 = 0.f;
    if (MODE != 0) {
        unpk(1, uload(R0 - 3));
        unpk(2, uload(R0 - 2));
        unpk(3, uload(R0 - 1));
        compI(R0 - 2, 0, 2, 3, 1);
        pu = uload(R0);
    }
    {
        int row = R0 - 1; bool ok = (((unsigned)row) < (unsigned)HH) && wok;
        int idx = boff + row * WW + w;
        pyv = ok ? y[idx] : 0.f;
        if (MODE == 1) {
            px2 = ok ? cf(x2_in[idx]) : 0.f;
            __half2 rv = ok ? *(const __half2*)(r2_in + 2 * (size_t)idx)
                            : __floats2half2_rn(0.f, 0.f);
            pr0 = __low2float(rv); pr1 = __high2float(rv);
        }
    }

    // ---- main pipeline: rr = R0-1 .. R0+HS+1 ----
    #pragma unroll
    for (int k = 0; k < HS + 3; ++k) {
        const int rr = R0 - 1 + k;
        uint2 nu; nu.x = 0u; nu.y = 0u;
        if (MODE != 0) { unpk(k & 3, pu); nu = uload(rr + 2); }
        float yv = pyv, x2v = px2, r20v = pr0, r21v = pr1;
        if (k < HS + 2) {
            int row = rr + 1; bool ok = (((unsigned)row) < (unsigned)HH) && wok;
            int idx = boff + row * WW + w;
            pyv = ok ? y[idx] : 0.f;
            if (MODE == 1) {
                px2 = ok ? cf(x2_in[idx]) : 0.f;
                __half2 rv = ok ? *(const __half2*)(r2_in + 2 * (size_t)idx)
                                : __floats2half2_rn(0.f, 0.f);
                pr0 = __low2float(rv); pr1 = __high2float(rv);
            }
        }
        if (MODE != 0) compI(rr, (k + 1) & 1, (k + 3) & 3, k & 3, (k + 2) & 3);
        compS(rr, (k + 3) & 3, (k + 1) & 1, k & 1, yv, x2v, r20v, r21v,
              (k >= 1 && k <= HS));
        if (k >= 3) compU(R0 - 3 + k, (k + 1) & 3, (k + 2) & 3, k & 3, (k + 3) & 3,
                          (k + 1) & 3);
        if (MODE != 0) pu = nu;
    }
}

extern "C" void kernel_launch(void* const* d_in, const int* in_sizes, int n_in,
                              void* d_out, int out_size, void* d_ws, size_t ws_size,
                              hipStream_t stream)
{
    const float* y   = (const float*)d_in[0];
    const int*   ths = (const int*)d_in[1];
    __half* ws = (__half*)d_ws;

    __half* Ax2 = ws;
    __half* Ar2 = ws + (size_t)NPIX;
    __half* Au  = ws + (size_t)3 * NPIX;
    __half* Bx2 = ws + (size_t)7 * NPIX;
    __half* Br2 = ws + (size_t)8 * NPIX;
    __half* Bu  = ws + (size_t)10 * NPIX;
    float*  xout = (float*)d_out;

    dim3 block(256);
    dim3 grid(NBLK);

    // iter 0 (analytic) -> B
    sweep<0><<<grid, block, 0, stream>>>(y, ths, Ax2, Ar2, Au, Bx2, Br2, Bu, nullptr);
    // iters 1..8 alternate
    __half *ix2 = Bx2, *ir2 = Br2, *iu = Bu;
    __half *ox2 = Ax2, *or2 = Ar2, *ou = Au;
    for (int it = 1; it <= 8; ++it) {
        sweep<1><<<grid, block, 0, stream>>>(y, ths, ix2, ir2, iu, ox2, or2, ou, nullptr);
        __half* t;
        t = ix2; ix2 = ox2; ox2 = t;
        t = ir2; ir2 = or2; or2 = t;
        t = iu;  iu  = ou;  ou  = t;
    }
    // iter 9: x only -> d_out (state now in ix2/iu)
    sweep<2><<<grid, block, 0, stream>>>(y, ths, ix2, ir2, iu, nullptr, nullptr, nullptr, xout);
}

// Round 2
// 180.868 us; speedup vs baseline: 1.1688x; 1.1688x over previous
//
#include <hip/hip_runtime.h>
#include <hip/hip_fp16.h>
#include <math.h>

#define HH 512
#define WW 512
#define BB 4
#define NPIX (BB * HH * WW)

#define HS 4                 // core rows per wave (must keep R0 % 4 == 0)
#define NSX 9                // strips: 9 x 60 core cols >= 512
#define NBAND (HH / HS)      // 128
#define NWAVES (NSX * NBAND * BB)   // 4608
#define NBLK (NWAVES / 4)           // 1152

constexpr float TAUf   = 0.01f;
constexpr float RHOf   = 1.99f;
constexpr float SIGMAf = (float)(1.0 / 0.01 / 72.0);
constexpr float INV1PT = (float)(1.0 / 1.01);

__device__ __forceinline__ float cf(__half h) { return __half2float(h); }
__device__ __forceinline__ float SD(float v) { return __shfl_down(v, 1, 64); }  // lane+1
__device__ __forceinline__ float SUp(float v) { return __shfl_up(v, 1, 64); }   // lane-1

// MODE: 0 = iter 0 (analytic x=y,r=0,u=0); 1 = mid iter; 2 = last iter (x-only, f32 out)
template <int MODE>
__global__ __launch_bounds__(256) void sweep(
    const float* __restrict__ y, const int* __restrict__ ths_p,
    const __half* __restrict__ x2_in, const __half* __restrict__ r2_in,
    const __half* __restrict__ u_in,
    __half* __restrict__ x2_out, __half* __restrict__ r2_out,
    __half* __restrict__ u_out, float* __restrict__ xout)
{
    const int tid  = threadIdx.x;
    const int lane = tid & 63;
    const int wid  = blockIdx.x * 4 + (tid >> 6);
    const int sx   = wid % NSX;
    const int t2   = wid / NSX;
    const int band = t2 & (NBAND - 1);
    const int b    = t2 / NBAND;
    const int R0   = band * HS;               // multiple of 4 -> ring slots are compile-time
    const int w    = sx * 60 - 2 + lane;
    const int boff = b * (HH * WW);
    const bool wok = ((unsigned)w) < (unsigned)WW;
    const float mA = (w >= 1 && w < WW) ? 1.f : 0.f;       // (w>=1) guard
    const float mB = (w >= 0 && w < WW - 1) ? 1.f : 0.f;   // (w<W-1) guard
    const bool cok = (lane >= 2) && (lane < 62) && (w < WW);

    const float ths     = (float)ths_p[0];
    const float inv_tl1 = 1.0f / (TAUf * (ths * 0.1f));
    const float inv_l2  = 1.0f / (ths * 0.15f);

    // register rings
    float uf0[4], uf1[4], uf2[4], uf3[4];     // u rows (unpacked f32)
    float i0r[2], i1r[2];                     // eps2_adj rows
    float sr[2];                              // s rows (rr&1)
    float t1r[2];                             // t1 rows (rr&1)
    float v0r[4];                             // v0(row) = mB*(s(row,w+1)-s(row,w)) - t0(row), slot row&3
    float v1r[2];                             // v1(row) = hD(row)*(s(row+1)-s(row)) - t1(row), slot row&1
    #pragma unroll
    for (int q = 0; q < 4; ++q) { uf0[q]=uf1[q]=uf2[q]=uf3[q]=0.f; v0r[q]=0.f; }
    i0r[0]=i0r[1]=i1r[0]=i1r[1]=0.f;
    sr[0]=sr[1]=0.f; t1r[0]=t1r[1]=0.f; v1r[0]=v1r[1]=0.f;

    auto uload = [&](int row) -> uint2 {
        uint2 z; z.x = 0u; z.y = 0u;
        if (((unsigned)row) < (unsigned)HH && wok)
            z = *(const uint2*)(u_in + 4 * (size_t)(boff + row * WW + w));
        return z;
    };
    auto unpk = [&](int slot, uint2 raw) {
        __half2 lo = *(reinterpret_cast<__half2*>(&raw.x));
        __half2 hi = *(reinterpret_cast<__half2*>(&raw.y));
        uf0[slot] = __low2float(lo); uf1[slot] = __high2float(lo);
        uf2[slot] = __low2float(hi); uf3[slot] = __high2float(hi);
    };
    // i(rr): islot, c = rr&3 (u row rr), d = (rr+1)&3, uu_ = (rr-1)&3
    auto compI = [&](int rr, int islot, int c, int d, int uu_) {
        if (((unsigned)rr) < (unsigned)HH) {
            float hD  = (rr < HH - 1) ? 1.f : 0.f;
            float u1c = uf1[c], u2c = uf2[c];
            i0r[islot] = uf0[c] - uf0[d] - SD(u1c) + mA * u1c;
            i1r[islot] = u2c - SD(u2c) - hD * uf3[c] + uf3[uu_];
        } else { i0r[islot] = 0.f; i1r[islot] = 0.f; }
    };

    if (MODE == 2) {
        // ---- last iter: only x output (f32) ----
        unpk(2, uload(R0 - 2));
        unpk(3, uload(R0 - 1));
        unpk(0, uload(R0));
        compI(R0 - 1, 1, 3, 0, 2);
        uint2 pu = uload(R0 + 1);
        float pyv, px2;
        {
            int row = R0; bool ok = wok;   // R0 in range always
            int idx = boff + row * WW + w;
            pyv = ok ? y[idx] : 0.f;
            px2 = ok ? cf(x2_in[idx]) : 0.f;
        }
        #pragma unroll
        for (int k = 0; k < HS; ++k) {
            const int rr = R0 + k;
            unpk((k + 1) & 3, pu);
            uint2 nu = uload(rr + 2);
            float yv = pyv, x2v = px2;
            if (k < HS - 1) {
                int row = rr + 1; bool ok = wok;
                int idx = boff + row * WW + w;
                pyv = ok ? y[idx] : 0.f;
                px2 = ok ? cf(x2_in[idx]) : 0.f;
            }
            compI(rr, k & 1, k & 3, (k + 1) & 3, (k + 3) & 3);
            float hD = (rr < HH - 1) ? 1.f : 0.f;
            float i0c = i0r[k & 1], i1c = i1r[k & 1], i1u = i1r[(k + 1) & 1];
            float i0l = SUp(i0c);
            float na = TAUf * (mA * i0l - mB * i0c + i1u - hD * i1c);
            float x = (x2v - na + TAUf * yv) * INV1PT;
            if (cok) xout[boff + rr * WW + w] = x2v + RHOf * (x - x2v);
            pu = nu;
        }
        return;
    }

    // s,t(rr); relax writes on core rows; returns s, t0, t1 for this row
    auto compS = [&](int rr, int isc, int isp,
                     float yv, float x2v, float r20v, float r21v, bool coreRow,
                     float &sOut, float &t0Out, float &t1Out) {
        if (((unsigned)rr) < (unsigned)HH) {
            if (MODE == 0) {
                sOut = yv; t0Out = 0.f; t1Out = 0.f;
                if (coreRow && cok) {
                    int idx = boff + rr * WW + w;
                    x2_out[idx] = __float2half(yv);
                    *(__half2*)(r2_out + 2 * (size_t)idx) = __floats2half2_rn(0.f, 0.f);
                }
            } else {
                float hD = (rr < HH - 1) ? 1.f : 0.f;
                float i0c = i0r[isc], i1c = i1r[isc], i1u = i1r[isp];
                float i0l = SUp(i0c);
                float na = TAUf * (mA * i0l - mB * i0c + i1u - hD * i1c);
                float x = (x2v - na + TAUf * yv) * INV1PT;
                float rr0 = r20v + TAUf * i0c;
                float rr1 = r21v + TAUf * i1c;
                float mag = sqrtf(rr0 * rr0 + rr1 * rr1) * inv_tl1;
                float rinv = 1.0f / fmaxf(mag, 1.0f);
                float r0 = rr0 - rr0 * rinv;
                float r1 = rr1 - rr1 * rinv;
                sOut  = 2.f * x  - x2v;
                t0Out = 2.f * r0 - r20v;
                t1Out = 2.f * r1 - r21v;
                if (coreRow && cok) {
                    int idx = boff + rr * WW + w;
                    x2_out[idx] = __float2half(x2v + RHOf * (x - x2v));
                    *(__half2*)(r2_out + 2 * (size_t)idx) = __floats2half2_rn(
                        r20v + RHOf * (r0 - r20v), r21v + RHOf * (r1 - r21v));
                }
            }
        } else { sOut = 0.f; t0Out = 0.f; t1Out = 0.f; }
    };

    // u'(ro) from v-rings:
    //   v0c=v0(ro), v0u=v0(ro-1), v1c=v1(ro), v1d=v1(ro+1), v0l/v1l = SUp of v0c/v1c
    auto compU = [&](int ro, int v0c_s, int v0u_s, int v1c_s, int v1d_s, int uslot) {
        float hD  = (ro < HH - 1) ? 1.f : 0.f;
        float v0c = v0r[v0c_s], v0u = v0r[v0u_s];
        float v1c = v1r[v1c_s], v1d = v1r[v1d_s];
        float v0l = SUp(v0c);
        float v1l = SUp(v1c);
        float G0 = v0c - v0u;
        float G1 = mA * (v0c - v0l);
        float G2 = v1c - mA * v1l;
        float G3 = hD * (v1d - v1c);
        float u0v, u1v, u2v, u3v;
        if (MODE == 0) { u0v = u1v = u2v = u3v = 0.f; }
        else { u0v = uf0[uslot]; u1v = uf1[uslot]; u2v = uf2[uslot]; u3v = uf3[uslot]; }
        float uu0 = u0v + SIGMAf * G0;
        float uu1 = u1v + SIGMAf * G1;
        float uu2 = u2v + SIGMAf * G2;
        float uu3 = u3v + SIGMAf * G3;
        float mag = sqrtf(uu0 * uu0 + uu1 * uu1 + uu2 * uu2 + uu3 * uu3) * inv_l2;
        float ui = 1.0f / fmaxf(mag, 1.0f);
        if (cok) {
            int idx = boff + ro * WW + w;
            __half2 lo = __floats2half2_rn(u0v + RHOf * (uu0 * ui - u0v),
                                           u1v + RHOf * (uu1 * ui - u1v));
            __half2 hi = __floats2half2_rn(u2v + RHOf * (uu2 * ui - u2v),
                                           u3v + RHOf * (uu3 * ui - u3v));
            uint2 st; st.x = *(unsigned*)&lo; st.y = *(unsigned*)&hi;
            *(uint2*)(u_out + 4 * (size_t)idx) = st;
        }
    };

    // ---- prologue ----
    uint2 pu; pu.x = 0u; pu.y = 0u;
    float pyv = 0.f, px2 = 0.f, pr0 = 0.f, pr1 = 0.f;
    if (MODE != 0) {
        unpk(1, uload(R0 - 3));
        unpk(2, uload(R0 - 2));
        unpk(3, uload(R0 - 1));
        compI(R0 - 2, 0, 2, 3, 1);
        pu = uload(R0);
    }
    {
        int row = R0 - 1; bool ok = (((unsigned)row) < (unsigned)HH) && wok;
        int idx = boff + row * WW + w;
        pyv = ok ? y[idx] : 0.f;
        if (MODE == 1) {
            px2 = ok ? cf(x2_in[idx]) : 0.f;
            __half2 rv = ok ? *(const __half2*)(r2_in + 2 * (size_t)idx)
                            : __floats2half2_rn(0.f, 0.f);
            pr0 = __low2float(rv); pr1 = __high2float(rv);
        }
    }

    // ---- main pipeline: rr = R0-1 .. R0+HS+1 ----
    // slot algebra (R0 % 4 == 0, rr = R0-1+k):
    //   rr&1 = (k+1)&1, (rr-1)&1 = k&1, rr&3 = (k+3)&3
    //   ro = rr-2: ro&3 = (k+1)&3, (ro-1)&3 = k&3, ro&1 = (k+1)&1, (ro+1)&1 = k&1
    #pragma unroll
    for (int k = 0; k < HS + 3; ++k) {
        const int rr = R0 - 1 + k;
        uint2 nu; nu.x = 0u; nu.y = 0u;
        if (MODE != 0) { unpk(k & 3, pu); nu = uload(rr + 2); }
        float yv = pyv, x2v = px2, r20v = pr0, r21v = pr1;
        if (k < HS + 2) {
            int row = rr + 1; bool ok = (((unsigned)row) < (unsigned)HH) && wok;
            int idx = boff + row * WW + w;
            pyv = ok ? y[idx] : 0.f;
            if (MODE == 1) {
                px2 = ok ? cf(x2_in[idx]) : 0.f;
                __half2 rv = ok ? *(const __half2*)(r2_in + 2 * (size_t)idx)
                                : __floats2half2_rn(0.f, 0.f);
                pr0 = __low2float(rv); pr1 = __high2float(rv);
            }
        }
        if (MODE != 0) compI(rr, (k + 1) & 1, (k + 3) & 3, k & 3, (k + 2) & 3);

        float sN, t0N, t1N;
        compS(rr, (k + 1) & 1, k & 1, yv, x2v, r20v, r21v,
              (k >= 1 && k <= HS), sN, t0N, t1N);

        // v-ring updates for row rr (v0) and row rr-1 (v1)
        {
            float sPrev  = sr[k & 1];            // s(rr-1)
            float t1Prev = t1r[k & 1];           // t1(rr-1)
            float hDm1   = (rr < HH) ? 1.f : 0.f; // hD(rr-1) = (rr-1 < HH-1)
            v0r[(k + 3) & 3] = mB * (SD(sN) - sN) - t0N;       // v0(rr)
            v1r[k & 1]       = hDm1 * (sN - sPrev) - t1Prev;   // v1(rr-1)
            sr[(k + 1) & 1]  = sN;               // s(rr)
            t1r[(k + 1) & 1] = t1N;              // t1(rr)
        }

        if (k >= 3) compU(R0 - 3 + k, (k + 1) & 3, k & 3, (k + 1) & 1, k & 1,
                          (k + 1) & 3);
        if (MODE != 0) pu = nu;
    }
}

extern "C" void kernel_launch(void* const* d_in, const int* in_sizes, int n_in,
                              void* d_out, int out_size, void* d_ws, size_t ws_size,
                              hipStream_t stream)
{
    const float* y   = (const float*)d_in[0];
    const int*   ths = (const int*)d_in[1];
    __half* ws = (__half*)d_ws;

    __half* Ax2 = ws;
    __half* Ar2 = ws + (size_t)NPIX;
    __half* Au  = ws + (size_t)3 * NPIX;
    __half* Bx2 = ws + (size_t)7 * NPIX;
    __half* Br2 = ws + (size_t)8 * NPIX;
    __half* Bu  = ws + (size_t)10 * NPIX;
    float*  xout = (float*)d_out;

    dim3 block(256);
    dim3 grid(NBLK);

    // iter 0 (analytic) -> B
    sweep<0><<<grid, block, 0, stream>>>(y, ths, Ax2, Ar2, Au, Bx2, Br2, Bu, nullptr);
    // iters 1..8 alternate
    __half *ix2 = Bx2, *ir2 = Br2, *iu = Bu;
    __half *ox2 = Ax2, *or2 = Ar2, *ou = Au;
    for (int it = 1; it <= 8; ++it) {
        sweep<1><<<grid, block, 0, stream>>>(y, ths, ix2, ir2, iu, ox2, or2, ou, nullptr);
        __half* t;
        t = ix2; ix2 = ox2; ox2 = t;
        t = ir2; ir2 = or2; or2 = t;
        t = iu;  iu  = ou;  ou  = t;
    }
    // iter 9: x only -> d_out (state now in ix2/iu)
    sweep<2><<<grid, block, 0, stream>>>(y, ths, ix2, ir2, iu, nullptr, nullptr, nullptr, xout);
}

// Round 4
// 170.607 us; speedup vs baseline: 1.2390x; 1.0601x over previous
//
#include <hip/hip_runtime.h>
#include <hip/hip_fp16.h>
#include <math.h>

#define HH 512
#define WW 512
#define BB 4
#define NPIX (BB * HH * WW)

#define HS 4                 // core rows per wave (must keep R0 % 4 == 0)
#define NSX 9                // strips: 9 x 60 core cols >= 512
#define NBAND (HH / HS)      // 128
#define NWAVES (NSX * NBAND * BB)   // 4608
#define NBLK (NWAVES / 4)           // 1152

constexpr float TAUf   = 0.01f;
constexpr float RHOf   = 1.99f;
constexpr float SIGMAf = (float)(1.0 / 0.01 / 72.0);
constexpr float INV1PT = (float)(1.0 / 1.01);

__device__ __forceinline__ float SD(float v) { return __shfl_down(v, 1, 64); }  // lane+1
__device__ __forceinline__ float SUp(float v) { return __shfl_up(v, 1, 64); }   // lane-1

// Fused state record F (uint2): .x = half2(x2, r0), .y = half2(r1, y_half)
// y_half bits are passed through unchanged every iteration (no re-rounding drift).

// MODE: 0 = iter 0 (analytic x=y,r=0,u=0); 1 = mid iter; 2 = last iter (x-only, f32 out)
template <int MODE>
__global__ __launch_bounds__(256) void sweep(
    const float* __restrict__ y, const int* __restrict__ ths_p,
    const uint2* __restrict__ f_in, const uint2* __restrict__ u_in,
    uint2* __restrict__ f_out, uint2* __restrict__ u_out,
    float* __restrict__ xout)
{
    const int tid  = threadIdx.x;
    const int lane = tid & 63;
    const int wid  = blockIdx.x * 4 + (tid >> 6);
    const int sx   = wid % NSX;
    const int t2   = wid / NSX;
    const int band = t2 & (NBAND - 1);
    const int b    = t2 / NBAND;
    const int R0   = band * HS;               // multiple of 4 -> ring slots are compile-time
    const int w    = sx * 60 - 2 + lane;
    const int boff = b * (HH * WW);
    const bool wok = ((unsigned)w) < (unsigned)WW;
    const float mA = (w >= 1 && w < WW) ? 1.f : 0.f;       // (w>=1) guard
    const float mB = (w >= 0 && w < WW - 1) ? 1.f : 0.f;   // (w<W-1) guard
    const bool cok = (lane >= 2) && (lane < 62) && (w < WW);

    const float ths     = (float)ths_p[0];
    const float inv_tl1 = 1.0f / (TAUf * (ths * 0.1f));
    const float inv_l2  = 1.0f / (ths * 0.15f);

    // register rings
    float uf0[4], uf1[4], uf2[4], uf3[4];     // u rows (unpacked f32)
    float i0r[2], i1r[2];                     // eps2_adj rows
    float sr[2];                              // s rows (rr&1)
    float t1r[2];                             // t1 rows (rr&1)
    float v0r[4];                             // v0(row), slot row&3
    float v1r[2];                             // v1(row), slot row&1
    #pragma unroll
    for (int q = 0; q < 4; ++q) { uf0[q]=uf1[q]=uf2[q]=uf3[q]=0.f; v0r[q]=0.f; }
    i0r[0]=i0r[1]=i1r[0]=i1r[1]=0.f;
    sr[0]=sr[1]=0.f; t1r[0]=t1r[1]=0.f; v1r[0]=v1r[1]=0.f;

    auto uload = [&](int row) -> uint2 {
        uint2 z; z.x = 0u; z.y = 0u;
        if (((unsigned)row) < (unsigned)HH && wok)
            z = u_in[(size_t)(boff + row * WW + w)];
        return z;
    };
    auto fload = [&](int row) -> uint2 {
        uint2 z; z.x = 0u; z.y = 0u;
        if (((unsigned)row) < (unsigned)HH && wok)
            z = f_in[(size_t)(boff + row * WW + w)];
        return z;
    };
    auto unpk = [&](int slot, uint2 raw) {
        __half2 lo = *(reinterpret_cast<__half2*>(&raw.x));
        __half2 hi = *(reinterpret_cast<__half2*>(&raw.y));
        uf0[slot] = __low2float(lo); uf1[slot] = __high2float(lo);
        uf2[slot] = __low2float(hi); uf3[slot] = __high2float(hi);
    };
    // i(rr): islot, c = rr&3 (u row rr), d = (rr+1)&3, uu_ = (rr-1)&3
    auto compI = [&](int rr, int islot, int c, int d, int uu_) {
        if (((unsigned)rr) < (unsigned)HH) {
            float hD  = (rr < HH - 1) ? 1.f : 0.f;
            float u1c = uf1[c], u2c = uf2[c];
            i0r[islot] = uf0[c] - uf0[d] - SD(u1c) + mA * u1c;
            i1r[islot] = u2c - SD(u2c) - hD * uf3[c] + uf3[uu_];
        } else { i0r[islot] = 0.f; i1r[islot] = 0.f; }
    };

    if (MODE == 2) {
        // ---- last iter: only x output (f32) ----
        unpk(2, uload(R0 - 2));
        unpk(3, uload(R0 - 1));
        unpk(0, uload(R0));
        compI(R0 - 1, 1, 3, 0, 2);
        uint2 pu = uload(R0 + 1);
        uint2 pf = fload(R0);
        #pragma unroll
        for (int k = 0; k < HS; ++k) {
            const int rr = R0 + k;
            unpk((k + 1) & 3, pu);
            uint2 nu = uload(rr + 2);
            __half2 lo = *(reinterpret_cast<__half2*>(&pf.x));
            __half2 hi = *(reinterpret_cast<__half2*>(&pf.y));
            float x2v = __low2float(lo);
            float yv  = __high2float(hi);
            if (k < HS - 1) pf = fload(rr + 1);
            compI(rr, k & 1, k & 3, (k + 1) & 3, (k + 3) & 3);
            float hD = (rr < HH - 1) ? 1.f : 0.f;
            float i0c = i0r[k & 1], i1c = i1r[k & 1], i1u = i1r[(k + 1) & 1];
            float i0l = SUp(i0c);
            float na = TAUf * (mA * i0l - mB * i0c + i1u - hD * i1c);
            float x = (x2v - na + TAUf * yv) * INV1PT;
            if (cok) xout[boff + rr * WW + w] = x2v + RHOf * (x - x2v);
            pu = nu;
        }
        return;
    }

    // s,t(rr); relax writes on core rows; returns s, t0, t1 for this row
    auto compS = [&](int rr, int isc, int isp,
                     float yv, float x2v, float r20v, float r21v, unsigned yraw,
                     bool coreRow, float &sOut, float &t0Out, float &t1Out) {
        if (((unsigned)rr) < (unsigned)HH) {
            if (MODE == 0) {
                sOut = yv; t0Out = 0.f; t1Out = 0.f;
                if (coreRow && cok) {
                    int idx = boff + rr * WW + w;
                    unsigned hb = (unsigned)__half_as_ushort(__float2half(yv));
                    uint2 st; st.x = hb; st.y = hb << 16;   // {x2=y, r0=0, r1=0, y}
                    f_out[(size_t)idx] = st;
                }
            } else {
                float hD = (rr < HH - 1) ? 1.f : 0.f;
                float i0c = i0r[isc], i1c = i1r[isc], i1u = i1r[isp];
                float i0l = SUp(i0c);
                float na = TAUf * (mA * i0l - mB * i0c + i1u - hD * i1c);
                float x = (x2v - na + TAUf * yv) * INV1PT;
                float rr0 = r20v + TAUf * i0c;
                float rr1 = r21v + TAUf * i1c;
                float mag = sqrtf(rr0 * rr0 + rr1 * rr1) * inv_tl1;
                float rinv = 1.0f / fmaxf(mag, 1.0f);
                float r0 = rr0 - rr0 * rinv;
                float r1 = rr1 - rr1 * rinv;
                sOut  = 2.f * x  - x2v;
                t0Out = 2.f * r0 - r20v;
                t1Out = 2.f * r1 - r21v;
                if (coreRow && cok) {
                    int idx = boff + rr * WW + w;
                    __half2 lo2 = __floats2half2_rn(x2v + RHOf * (x - x2v),
                                                    r20v + RHOf * (r0 - r20v));
                    unsigned r1b = (unsigned)__half_as_ushort(
                        __float2half(r21v + RHOf * (r1 - r21v)));
                    uint2 st; st.x = *(unsigned*)&lo2; st.y = r1b | (yraw << 16);
                    f_out[(size_t)idx] = st;
                }
            }
        } else { sOut = 0.f; t0Out = 0.f; t1Out = 0.f; }
    };

    // u'(ro) from v-rings:
    //   v0c=v0(ro), v0u=v0(ro-1), v1c=v1(ro), v1d=v1(ro+1), v0l/v1l = SUp of v0c/v1c
    auto compU = [&](int ro, int v0c_s, int v0u_s, int v1c_s, int v1d_s, int uslot) {
        float hD  = (ro < HH - 1) ? 1.f : 0.f;
        float v0c = v0r[v0c_s], v0u = v0r[v0u_s];
        float v1c = v1r[v1c_s], v1d = v1r[v1d_s];
        float v0l = SUp(v0c);
        float v1l = SUp(v1c);
        float G0 = v0c - v0u;
        float G1 = mA * (v0c - v0l);
        float G2 = v1c - mA * v1l;
        float G3 = hD * (v1d - v1c);
        float u0v, u1v, u2v, u3v;
        if (MODE == 0) { u0v = u1v = u2v = u3v = 0.f; }
        else { u0v = uf0[uslot]; u1v = uf1[uslot]; u2v = uf2[uslot]; u3v = uf3[uslot]; }
        float uu0 = u0v + SIGMAf * G0;
        float uu1 = u1v + SIGMAf * G1;
        float uu2 = u2v + SIGMAf * G2;
        float uu3 = u3v + SIGMAf * G3;
        float mag = sqrtf(uu0 * uu0 + uu1 * uu1 + uu2 * uu2 + uu3 * uu3) * inv_l2;
        float ui = 1.0f / fmaxf(mag, 1.0f);
        if (cok) {
            int idx = boff + ro * WW + w;
            __half2 lo = __floats2half2_rn(u0v + RHOf * (uu0 * ui - u0v),
                                           u1v + RHOf * (uu1 * ui - u1v));
            __half2 hi = __floats2half2_rn(u2v + RHOf * (uu2 * ui - u2v),
                                           u3v + RHOf * (uu3 * ui - u3v));
            uint2 st; st.x = *(unsigned*)&lo; st.y = *(unsigned*)&hi;
            u_out[(size_t)idx] = st;
        }
    };

    // ---- prologue ----
    uint2 pu; pu.x = 0u; pu.y = 0u;
    uint2 pf; pf.x = 0u; pf.y = 0u;
    float pyv = 0.f;
    if (MODE != 0) {
        unpk(1, uload(R0 - 3));
        unpk(2, uload(R0 - 2));
        unpk(3, uload(R0 - 1));
        compI(R0 - 2, 0, 2, 3, 1);
        pu = uload(R0);
        pf = fload(R0 - 1);
    } else {
        int row = R0 - 1; bool ok = (((unsigned)row) < (unsigned)HH) && wok;
        pyv = ok ? y[boff + row * WW + w] : 0.f;
    }

    // ---- main pipeline: rr = R0-1 .. R0+HS+1 ----
    // slot algebra (R0 % 4 == 0, rr = R0-1+k):
    //   rr&1 = (k+1)&1, (rr-1)&1 = k&1, rr&3 = (k+3)&3
    //   ro = rr-2: ro&3 = (k+1)&3, (ro-1)&3 = k&3, ro&1 = (k+1)&1, (ro+1)&1 = k&1
    #pragma unroll
    for (int k = 0; k < HS + 3; ++k) {
        const int rr = R0 - 1 + k;
        uint2 nu; nu.x = 0u; nu.y = 0u;
        if (MODE != 0) { unpk(k & 3, pu); nu = uload(rr + 2); }

        float yv, x2v = 0.f, r20v = 0.f, r21v = 0.f; unsigned yraw = 0u;
        if (MODE == 1) {
            __half2 lo = *(reinterpret_cast<__half2*>(&pf.x));
            __half2 hi = *(reinterpret_cast<__half2*>(&pf.y));
            x2v  = __low2float(lo);  r20v = __high2float(lo);
            r21v = __low2float(hi);  yv   = __high2float(hi);
            yraw = pf.y >> 16;
        } else {
            yv = pyv;
        }
        if (k < HS + 2) {
            int row = rr + 1;
            if (MODE == 1) {
                pf = fload(row);
            } else {
                bool ok = (((unsigned)row) < (unsigned)HH) && wok;
                pyv = ok ? y[boff + row * WW + w] : 0.f;
            }
        }
        if (MODE != 0) compI(rr, (k + 1) & 1, (k + 3) & 3, k & 3, (k + 2) & 3);

        float sN, t0N, t1N;
        compS(rr, (k + 1) & 1, k & 1, yv, x2v, r20v, r21v, yraw,
              (k >= 1 && k <= HS), sN, t0N, t1N);

        // v-ring updates for row rr (v0) and row rr-1 (v1)
        {
            float sPrev  = sr[k & 1];             // s(rr-1)
            float t1Prev = t1r[k & 1];            // t1(rr-1)
            float hDm1   = (rr < HH) ? 1.f : 0.f; // hD(rr-1) = (rr-1 < HH-1)
            v0r[(k + 3) & 3] = mB * (SD(sN) - sN) - t0N;       // v0(rr)
            v1r[k & 1]       = hDm1 * (sN - sPrev) - t1Prev;   // v1(rr-1)
            sr[(k + 1) & 1]  = sN;                // s(rr)
            t1r[(k + 1) & 1] = t1N;               // t1(rr)
        }

        if (k >= 3) compU(R0 - 3 + k, (k + 1) & 3, k & 3, (k + 1) & 1, k & 1,
                          (k + 1) & 3);
        if (MODE != 0) pu = nu;
    }
}

extern "C" void kernel_launch(void* const* d_in, const int* in_sizes, int n_in,
                              void* d_out, int out_size, void* d_ws, size_t ws_size,
                              hipStream_t stream)
{
    const float* y   = (const float*)d_in[0];
    const int*   ths = (const int*)d_in[1];
    uint2* ws2 = (uint2*)d_ws;

    uint2* FA = ws2;
    uint2* UA = ws2 + (size_t)NPIX;
    uint2* FB = ws2 + 2 * (size_t)NPIX;
    uint2* UB = ws2 + 3 * (size_t)NPIX;
    float* xout = (float*)d_out;

    dim3 block(256);
    dim3 grid(NBLK);

    // iter 0 (analytic) -> B
    sweep<0><<<grid, block, 0, stream>>>(y, ths, nullptr, nullptr, FB, UB, nullptr);
    // iters 1..8 alternate
    uint2 *fi = FB, *ui = UB, *fo = FA, *uo = UA;
    for (int it = 1; it <= 8; ++it) {
        sweep<1><<<grid, block, 0, stream>>>(y, ths, fi, ui, fo, uo, nullptr);
        uint2* t;
        t = fi; fi = fo; fo = t;
        t = ui; ui = uo; uo = t;
    }
    // iter 9: x only -> d_out
    sweep<2><<<grid, block, 0, stream>>>(y, ths, fi, ui, nullptr, nullptr, xout);
}

// Round 5
// 160.200 us; speedup vs baseline: 1.3195x; 1.0650x over previous
//
#include <hip/hip_runtime.h>
#include <hip/hip_fp16.h>
#include <math.h>

#define HH 512
#define WW 512
#define BB 4
#define NPIX (BB * HH * WW)

#define HS 4                 // core rows per wave (must keep R0 % 4 == 0)
#define NSX 9                // strips: 9 x 60 core cols >= 512
#define NBAND (HH / HS)      // 128
#define NWAVES (NSX * NBAND * BB)   // 4608
#define NBLK (NWAVES / 4)           // 1152

constexpr float TAUf   = 0.01f;
constexpr float RHOf   = 1.99f;
constexpr float SIGMAf = (float)(1.0 / 0.01 / 72.0);
constexpr float INV1PT = (float)(1.0 / 1.01);

__device__ __forceinline__ float SD(float v) { return __shfl_down(v, 1, 64); }  // lane+1
__device__ __forceinline__ float SUp(float v) { return __shfl_up(v, 1, 64); }   // lane-1

// Fused state record F (uint2): .x = half2(x2, r0), .y = half2(r1, y_half)
// y_half bits are passed through unchanged every iteration (no re-rounding drift).

// MODE: 0 = iter 0 (analytic x=y,r=0,u=0); 1 = mid iter; 2 = last iter (x-only, f32 out)
template <int MODE>
__global__ __launch_bounds__(256) void sweep(
    const float* __restrict__ y, const int* __restrict__ ths_p,
    const uint2* __restrict__ f_in, const uint2* __restrict__ u_in,
    uint2* __restrict__ f_out, uint2* __restrict__ u_out,
    float* __restrict__ xout)
{
    const int tid  = threadIdx.x;
    const int lane = tid & 63;
    const int wid  = blockIdx.x * 4 + (tid >> 6);
    const int sx   = wid % NSX;
    const int t2   = wid / NSX;
    const int band = t2 & (NBAND - 1);
    const int b    = t2 / NBAND;
    const int R0   = band * HS;               // multiple of 4 -> ring slots are compile-time
    const int w    = sx * 60 - 2 + lane;
    const int boff = b * (HH * WW);
    const bool wok = ((unsigned)w) < (unsigned)WW;
    const float mA = (w >= 1 && w < WW) ? 1.f : 0.f;       // (w>=1) guard
    const float mB = (w >= 0 && w < WW - 1) ? 1.f : 0.f;   // (w<W-1) guard
    const bool cok = (lane >= 2) && (lane < 62) && (w < WW);

    const float ths  = (float)ths_p[0];
    const float tl1_ = TAUf * (ths * 0.1f);   // for rinv = min(tl1_*rsq(d), 1)
    const float l2_  = ths * 0.15f;           // for ui   = min(l2_ *rsq(d), 1)

    // register rings
    float uf0[4], uf1[4], uf2[4], uf3[4];     // u rows (unpacked f32)
    float i0r[2], i1r[2];                     // eps2_adj rows
    float sr[2];                              // s rows (rr&1)
    float t1r[2];                             // t1 rows (rr&1)
    float v0r[4];                             // v0(row), slot row&3
    float v1r[2];                             // v1(row), slot row&1
    #pragma unroll
    for (int q = 0; q < 4; ++q) { uf0[q]=uf1[q]=uf2[q]=uf3[q]=0.f; v0r[q]=0.f; }
    i0r[0]=i0r[1]=i1r[0]=i1r[1]=0.f;
    sr[0]=sr[1]=0.f; t1r[0]=t1r[1]=0.f; v1r[0]=v1r[1]=0.f;

    auto uload = [&](int row) -> uint2 {
        uint2 z; z.x = 0u; z.y = 0u;
        if (((unsigned)row) < (unsigned)HH && wok)
            z = u_in[(size_t)(boff + row * WW + w)];
        return z;
    };
    auto fload = [&](int row) -> uint2 {
        uint2 z; z.x = 0u; z.y = 0u;
        if (((unsigned)row) < (unsigned)HH && wok)
            z = f_in[(size_t)(boff + row * WW + w)];
        return z;
    };
    auto unpk = [&](int slot, uint2 raw) {
        __half2 lo = *(reinterpret_cast<__half2*>(&raw.x));
        __half2 hi = *(reinterpret_cast<__half2*>(&raw.y));
        uf0[slot] = __low2float(lo); uf1[slot] = __high2float(lo);
        uf2[slot] = __low2float(hi); uf3[slot] = __high2float(hi);
    };
    // i(rr): islot, c = rr&3 (u row rr), d = (rr+1)&3, uu_ = (rr-1)&3
    auto compI = [&](int rr, int islot, int c, int d, int uu_) {
        if (((unsigned)rr) < (unsigned)HH) {
            float hD  = (rr < HH - 1) ? 1.f : 0.f;
            float u1c = uf1[c], u2c = uf2[c];
            i0r[islot] = uf0[c] - uf0[d] - SD(u1c) + mA * u1c;
            i1r[islot] = u2c - SD(u2c) - hD * uf3[c] + uf3[uu_];
        } else { i0r[islot] = 0.f; i1r[islot] = 0.f; }
    };

    if (MODE == 2) {
        // ---- last iter: only x output (f32), 2-deep prefetch ----
        unpk(2, uload(R0 - 2));
        unpk(3, uload(R0 - 1));
        unpk(0, uload(R0));
        compI(R0 - 1, 1, 3, 0, 2);
        uint2 puA = uload(R0 + 1);
        uint2 puB = uload(R0 + 2);
        uint2 pfA = fload(R0);
        uint2 pfB = fload(R0 + 1);
        #pragma unroll
        for (int k = 0; k < HS; ++k) {
            const int rr = R0 + k;
            unpk((k + 1) & 3, puA);
            puA = puB;
            if (k < HS - 2) puB = uload(R0 + k + 3);
            __half2 lo = *(reinterpret_cast<__half2*>(&pfA.x));
            __half2 hi = *(reinterpret_cast<__half2*>(&pfA.y));
            float x2v = __low2float(lo);
            float yv  = __high2float(hi);
            pfA = pfB;
            if (k < HS - 2) pfB = fload(R0 + k + 2);
            compI(rr, k & 1, k & 3, (k + 1) & 3, (k + 3) & 3);
            float hD = (rr < HH - 1) ? 1.f : 0.f;
            float i0c = i0r[k & 1], i1c = i1r[k & 1], i1u = i1r[(k + 1) & 1];
            float i0l = SUp(i0c);
            float na = TAUf * (mA * i0l - mB * i0c + i1u - hD * i1c);
            float x = (x2v - na + TAUf * yv) * INV1PT;
            if (cok) xout[boff + rr * WW + w] = x2v + RHOf * (x - x2v);
        }
        return;
    }

    // s,t(rr); relax writes on core rows; returns s, t0, t1 for this row
    auto compS = [&](int rr, int isc, int isp,
                     float yv, float x2v, float r20v, float r21v, unsigned yraw,
                     bool coreRow, float &sOut, float &t0Out, float &t1Out) {
        if (((unsigned)rr) < (unsigned)HH) {
            if (MODE == 0) {
                sOut = yv; t0Out = 0.f; t1Out = 0.f;
                if (coreRow && cok) {
                    int idx = boff + rr * WW + w;
                    unsigned hb = (unsigned)__half_as_ushort(__float2half(yv));
                    uint2 st; st.x = hb; st.y = hb << 16;   // {x2=y, r0=0, r1=0, y}
                    f_out[(size_t)idx] = st;
                }
            } else {
                float hD = (rr < HH - 1) ? 1.f : 0.f;
                float i0c = i0r[isc], i1c = i1r[isc], i1u = i1r[isp];
                float i0l = SUp(i0c);
                float na = TAUf * (mA * i0l - mB * i0c + i1u - hD * i1c);
                float x = (x2v - na + TAUf * yv) * INV1PT;
                float rr0 = r20v + TAUf * i0c;
                float rr1 = r21v + TAUf * i1c;
                float d = rr0 * rr0 + rr1 * rr1;
                float rinv = fminf(tl1_ * __builtin_amdgcn_rsqf(d), 1.0f);
                float r0 = rr0 - rr0 * rinv;
                float r1 = rr1 - rr1 * rinv;
                sOut  = 2.f * x  - x2v;
                t0Out = 2.f * r0 - r20v;
                t1Out = 2.f * r1 - r21v;
                if (coreRow && cok) {
                    int idx = boff + rr * WW + w;
                    __half2 lo2 = __floats2half2_rn(x2v + RHOf * (x - x2v),
                                                    r20v + RHOf * (r0 - r20v));
                    unsigned r1b = (unsigned)__half_as_ushort(
                        __float2half(r21v + RHOf * (r1 - r21v)));
                    uint2 st; st.x = *(unsigned*)&lo2; st.y = r1b | (yraw << 16);
                    f_out[(size_t)idx] = st;
                }
            }
        } else { sOut = 0.f; t0Out = 0.f; t1Out = 0.f; }
    };

    // u'(ro) from v-rings:
    //   v0c=v0(ro), v0u=v0(ro-1), v1c=v1(ro), v1d=v1(ro+1), v0l/v1l = SUp of v0c/v1c
    auto compU = [&](int ro, int v0c_s, int v0u_s, int v1c_s, int v1d_s, int uslot) {
        float hD  = (ro < HH - 1) ? 1.f : 0.f;
        float v0c = v0r[v0c_s], v0u = v0r[v0u_s];
        float v1c = v1r[v1c_s], v1d = v1r[v1d_s];
        float v0l = SUp(v0c);
        float v1l = SUp(v1c);
        float G0 = v0c - v0u;
        float G1 = mA * (v0c - v0l);
        float G2 = v1c - mA * v1l;
        float G3 = hD * (v1d - v1c);
        float u0v, u1v, u2v, u3v;
        if (MODE == 0) { u0v = u1v = u2v = u3v = 0.f; }
        else { u0v = uf0[uslot]; u1v = uf1[uslot]; u2v = uf2[uslot]; u3v = uf3[uslot]; }
        float uu0 = u0v + SIGMAf * G0;
        float uu1 = u1v + SIGMAf * G1;
        float uu2 = u2v + SIGMAf * G2;
        float uu3 = u3v + SIGMAf * G3;
        float d = uu0 * uu0 + uu1 * uu1 + uu2 * uu2 + uu3 * uu3;
        float ui = fminf(l2_ * __builtin_amdgcn_rsqf(d), 1.0f);
        if (cok) {
            int idx = boff + ro * WW + w;
            __half2 lo = __floats2half2_rn(u0v + RHOf * (uu0 * ui - u0v),
                                           u1v + RHOf * (uu1 * ui - u1v));
            __half2 hi = __floats2half2_rn(u2v + RHOf * (uu2 * ui - u2v),
                                           u3v + RHOf * (uu3 * ui - u3v));
            uint2 st; st.x = *(unsigned*)&lo; st.y = *(unsigned*)&hi;
            u_out[(size_t)idx] = st;
        }
    };

    // ---- prologue (2-deep prefetch) ----
    uint2 puA, puB, pfA, pfB;
    puA.x = puA.y = puB.x = puB.y = 0u;
    pfA.x = pfA.y = pfB.x = pfB.y = 0u;
    float pyA = 0.f, pyB = 0.f;
    if (MODE != 0) {
        unpk(1, uload(R0 - 3));
        unpk(2, uload(R0 - 2));
        unpk(3, uload(R0 - 1));
        compI(R0 - 2, 0, 2, 3, 1);
        puA = uload(R0);          // unpack at k=0
        puB = uload(R0 + 1);      // unpack at k=1
        pfA = fload(R0 - 1);      // consume at k=0
        pfB = fload(R0);          // consume at k=1
    } else {
        int rowA = R0 - 1; bool okA = (((unsigned)rowA) < (unsigned)HH) && wok;
        pyA = okA ? y[boff + rowA * WW + w] : 0.f;
        pyB = wok ? y[boff + R0 * WW + w] : 0.f;   // row R0 always in range
    }

    // ---- main pipeline: rr = R0-1 .. R0+HS+1 ----
    // slot algebra (R0 % 4 == 0, rr = R0-1+k):
    //   rr&1 = (k+1)&1, (rr-1)&1 = k&1, rr&3 = (k+3)&3
    //   ro = rr-2: ro&3 = (k+1)&3, (ro-1)&3 = k&3, ro&1 = (k+1)&1, (ro+1)&1 = k&1
    #pragma unroll
    for (int k = 0; k < HS + 3; ++k) {
        const int rr = R0 - 1 + k;

        float yv, x2v = 0.f, r20v = 0.f, r21v = 0.f; unsigned yraw = 0u;
        if (MODE != 0) {
            unpk(k & 3, puA);               // u row R0+k (loaded at stage k-2)
            puA = puB;
            if (k <= HS) puB = uload(R0 + k + 2);   // rows R0+2 .. R0+HS+2
            __half2 lo = *(reinterpret_cast<__half2*>(&pfA.x));
            __half2 hi = *(reinterpret_cast<__half2*>(&pfA.y));
            x2v  = __low2float(lo);  r20v = __high2float(lo);
            r21v = __low2float(hi);  yv   = __high2float(hi);
            yraw = pfA.y >> 16;
            pfA = pfB;
            if (k <= HS) pfB = fload(R0 + k + 1);   // rows R0+1 .. R0+HS+1
        } else {
            yv = pyA;
            pyA = pyB;
            if (k <= HS) {
                int row = R0 + k + 1;
                bool ok = (((unsigned)row) < (unsigned)HH) && wok;
                pyB = ok ? y[boff + row * WW + w] : 0.f;
            }
        }
        if (MODE != 0) compI(rr, (k + 1) & 1, (k + 3) & 3, k & 3, (k + 2) & 3);

        float sN, t0N, t1N;
        compS(rr, (k + 1) & 1, k & 1, yv, x2v, r20v, r21v, yraw,
              (k >= 1 && k <= HS), sN, t0N, t1N);

        // v-ring updates for row rr (v0) and row rr-1 (v1)
        {
            float sPrev  = sr[k & 1];             // s(rr-1)
            float t1Prev = t1r[k & 1];            // t1(rr-1)
            float hDm1   = (rr < HH) ? 1.f : 0.f; // hD(rr-1) = (rr-1 < HH-1)
            v0r[(k + 3) & 3] = mB * (SD(sN) - sN) - t0N;       // v0(rr)
            v1r[k & 1]       = hDm1 * (sN - sPrev) - t1Prev;   // v1(rr-1)
            sr[(k + 1) & 1]  = sN;                // s(rr)
            t1r[(k + 1) & 1] = t1N;               // t1(rr)
        }

        if (k >= 3) compU(R0 - 3 + k, (k + 1) & 3, k & 3, (k + 1) & 1, k & 1,
                          (k + 1) & 3);
    }
}

extern "C" void kernel_launch(void* const* d_in, const int* in_sizes, int n_in,
                              void* d_out, int out_size, void* d_ws, size_t ws_size,
                              hipStream_t stream)
{
    const float* y   = (const float*)d_in[0];
    const int*   ths = (const int*)d_in[1];
    uint2* ws2 = (uint2*)d_ws;

    uint2* FA = ws2;
    uint2* UA = ws2 + (size_t)NPIX;
    uint2* FB = ws2 + 2 * (size_t)NPIX;
    uint2* UB = ws2 + 3 * (size_t)NPIX;
    float* xout = (float*)d_out;

    dim3 block(256);
    dim3 grid(NBLK);

    // iter 0 (analytic) -> B
    sweep<0><<<grid, block, 0, stream>>>(y, ths, nullptr, nullptr, FB, UB, nullptr);
    // iters 1..8 alternate
    uint2 *fi = FB, *ui = UB, *fo = FA, *uo = UA;
    for (int it = 1; it <= 8; ++it) {
        sweep<1><<<grid, block, 0, stream>>>(y, ths, fi, ui, fo, uo, nullptr);
        uint2* t;
        t = fi; fi = fo; fo = t;
        t = ui; ui = uo; uo = t;
    }
    // iter 9: x only -> d_out
    sweep<2><<<grid, block, 0, stream>>>(y, ths, fi, ui, nullptr, nullptr, xout);
}